// Round 9
// baseline (846.354 us; speedup 1.0000x reference)
//
#include <hip/hip_runtime.h>
#include <math.h>

typedef float floatx4 __attribute__((ext_vector_type(4)));
typedef _Float16 f16x8 __attribute__((ext_vector_type(8)));
typedef _Float16 f16x4 __attribute__((ext_vector_type(4)));

template<int N> struct f16vec_t;
template<> struct f16vec_t<4> { typedef f16x4 type; };
template<> struct f16vec_t<8> { typedef f16x8 type; };

// ---------- helpers ----------
__device__ __forceinline__ unsigned encf(float f) {
    unsigned u = __float_as_uint(f);
    return (u & 0x80000000u) ? ~u : (u | 0x80000000u);
}
__device__ __forceinline__ float decf(unsigned u) {
    u = (u & 0x80000000u) ? (u & 0x7FFFFFFFu) : ~u;
    return __uint_as_float(u);
}
// async global->LDS, 16 B per lane; LDS dst = wave-uniform base + lane*16
__device__ __forceinline__ void glds16(const void* g, void* l) {
    __builtin_amdgcn_global_load_lds(
        (const __attribute__((address_space(1))) unsigned int*)g,
        (__attribute__((address_space(3))) unsigned int*)l, 16, 0, 0);
}

// ---------- fp32 -> fp16 convert (vec4) ----------
__global__ __launch_bounds__(256) void cvt_f16_kernel(
    const float* __restrict__ in, _Float16* __restrict__ out, size_t n4)
{
    size_t i = (size_t)blockIdx.x * 256 + threadIdx.x;
    if (i >= n4) return;
    float4 v = ((const float4*)in)[i];
    f16x4 o;
    o[0] = (_Float16)v.x; o[1] = (_Float16)v.y; o[2] = (_Float16)v.z; o[3] = (_Float16)v.w;
    ((f16x4*)out)[i] = o;
}

// ---------- weight transpose + convert: w[K,N] fp32 -> wt[N,K] fp16 ----------
__global__ __launch_bounds__(256) void wt_kernel(
    const float* __restrict__ w, _Float16* __restrict__ wt, int K, int N)
{
    __shared__ float t[32][33];
    int bx = blockIdx.x * 32, by = blockIdx.y * 32;   // bx: n, by: k
    int tx = threadIdx.x & 31, ty = threadIdx.x >> 5; // 32x8
    for (int r = ty; r < 32; r += 8)
        t[r][tx] = w[(size_t)(by + r) * N + bx + tx];
    __syncthreads();
    for (int r = ty; r < 32; r += 8)
        wt[(size_t)(bx + r) * K + by + tx] = (_Float16)t[tx][r];
}

// ---------- fp16 MFMA GEMM, dbuf global_load_lds + fused attention scores ----------
// C[M,N] = A[M,K] @ B, BT=[N,K]. 128x128 tile, BK=32, 256 threads.
// If asrc != nullptr: atomically accumulates es[row*H+head] += sum_col C*asrc,
// ed likewise (head = col0>>8 is block-uniform since 128 | 256).
__global__ __launch_bounds__(256) void gemm_f16(
    const _Float16* __restrict__ A, const _Float16* __restrict__ BT,
    const float* __restrict__ bias, _Float16* __restrict__ C,
    const float* __restrict__ asrc, const float* __restrict__ adst,
    float* __restrict__ es, float* __restrict__ ed,
    int M, int K, int N, int act, int H)
{
    __shared__ _Float16 Al[2][128 * 32];
    __shared__ _Float16 Bl[2][128 * 32];
    int tid = threadIdx.x;
    int lane = tid & 63, wave = tid >> 6;
    int row0 = blockIdx.y * 128, col0 = blockIdx.x * 128;
    int wm = (wave >> 1) * 64, wn = (wave & 1) * 64;
    int l15 = lane & 15, quad = lane >> 4;

    int rg0 = wave * 2, rg1 = rg0 + 1;
    int srow0 = rg0 * 16 + (lane >> 2);
    int srow1 = rg1 * 16 + (lane >> 2);
    int scol = (lane & 3) * 8;
    int arow0 = row0 + srow0; if (arow0 > M - 1) arow0 = M - 1;
    int arow1 = row0 + srow1; if (arow1 > M - 1) arow1 = M - 1;
    const _Float16* gA0 = A + (size_t)arow0 * K + scol;
    const _Float16* gA1 = A + (size_t)arow1 * K + scol;
    const _Float16* gB0 = BT + (size_t)(col0 + srow0) * K + scol;
    const _Float16* gB1 = BT + (size_t)(col0 + srow1) * K + scol;

    floatx4 acc[4][4] = {};

    glds16(gA0, &Al[0][rg0 * 512]);
    glds16(gA1, &Al[0][rg1 * 512]);
    glds16(gB0, &Bl[0][rg0 * 512]);
    glds16(gB1, &Bl[0][rg1 * 512]);

    int nk = K >> 5;
    for (int it = 0; it < nk; it++) {
        int cur = it & 1, nxt = cur ^ 1;
        __syncthreads();
        if (it + 1 < nk) {
            int k1 = (it + 1) << 5;
            glds16(gA0 + k1, &Al[nxt][rg0 * 512]);
            glds16(gA1 + k1, &Al[nxt][rg1 * 512]);
            glds16(gB0 + k1, &Bl[nxt][rg0 * 512]);
            glds16(gB1 + k1, &Bl[nxt][rg1 * 512]);
        }
        f16x8 af[4], bfr[4];
        #pragma unroll
        for (int i = 0; i < 4; i++) {
            af[i]  = *(const f16x8*)&Al[cur][(wm + i * 16 + l15) * 32 + quad * 8];
            bfr[i] = *(const f16x8*)&Bl[cur][(wn + i * 16 + l15) * 32 + quad * 8];
        }
        #pragma unroll
        for (int i = 0; i < 4; i++)
            #pragma unroll
            for (int j = 0; j < 4; j++)
                acc[i][j] = __builtin_amdgcn_mfma_f32_16x16x32_f16(af[i], bfr[j], acc[i][j], 0, 0, 0);
    }

    // epilogue: D row = quad*4+reg, col = l15
    #pragma unroll
    for (int i = 0; i < 4; i++) {
        #pragma unroll
        for (int v = 0; v < 4; v++) {
            int gr = row0 + wm + i * 16 + quad * 4 + v;
            if (gr >= M) continue;
            #pragma unroll
            for (int j = 0; j < 4; j++) {
                int gc = col0 + wn + j * 16 + l15;
                float val = acc[i][j][v];
                if (bias) val += bias[gc];
                if (act) val = val > 0.f ? val : (expf(val) - 1.f);
                C[(size_t)gr * N + gc] = (_Float16)val;
            }
        }
    }

    // fused attention scores (gat GEMMs: bias=null, act=0 -> val == acc)
    if (asrc) {
        int head = col0 >> 8;                   // 128 | 256 => block-uniform
        int cbase = (col0 & 255) + wn;
        #pragma unroll
        for (int i = 0; i < 4; i++) {
            #pragma unroll
            for (int v = 0; v < 4; v++) {
                float ss = 0.f, sd = 0.f;
                #pragma unroll
                for (int j = 0; j < 4; j++) {
                    float val = acc[i][j][v];
                    int cc = cbase + j * 16 + l15;
                    ss = fmaf(val, asrc[head * 256 + cc], ss);
                    sd = fmaf(val, adst[head * 256 + cc], sd);
                }
                #pragma unroll
                for (int o = 1; o < 16; o <<= 1) {
                    ss += __shfl_xor(ss, o);
                    sd += __shfl_xor(sd, o);
                }
                int gr = row0 + wm + i * 16 + quad * 4 + v;
                if (l15 == 0 && gr < M) {
                    atomicAdd(&es[gr * H + head], ss);
                    atomicAdd(&ed[gr * H + head], sd);
                }
            }
        }
    }
}

// ---------- CSR build ----------
__global__ __launch_bounds__(256) void csr_init(int* __restrict__ deg, int Nn) {
    int i = blockIdx.x * 256 + threadIdx.x;
    if (i < Nn) deg[i] = 1;               // self-loop
}
__global__ __launch_bounds__(256) void csr_count(const int* __restrict__ ei, int* __restrict__ deg, int E) {
    int i = blockIdx.x * 256 + threadIdx.x;
    if (i < E) atomicAdd(&deg[ei[E + i]], 1);
}
__global__ __launch_bounds__(256) void scan1(const int* __restrict__ deg, int* __restrict__ incl,
                                             int* __restrict__ bsums, int Nn) {
    __shared__ int sd[256];
    int idx = blockIdx.x * 256 + threadIdx.x;
    sd[threadIdx.x] = (idx < Nn) ? deg[idx] : 0;
    __syncthreads();
    for (int o = 1; o < 256; o <<= 1) {
        int x = (threadIdx.x >= (unsigned)o) ? sd[threadIdx.x - o] : 0;
        __syncthreads();
        sd[threadIdx.x] += x;
        __syncthreads();
    }
    if (idx < Nn) incl[idx] = sd[threadIdx.x];
    if (threadIdx.x == 255) bsums[blockIdx.x] = sd[255];
}
__global__ void scan2(int* __restrict__ bsums, int nb) {
    if (blockIdx.x == 0 && threadIdx.x == 0) {
        int run = 0;
        for (int i = 0; i < nb; i++) { int v = bsums[i]; bsums[i] = run; run += v; }
    }
}
__global__ __launch_bounds__(256) void scan3(const int* __restrict__ incl, const int* __restrict__ deg,
                                             const int* __restrict__ bsums, int* __restrict__ rowstart,
                                             int* __restrict__ cursor, int Nn) {
    int idx = blockIdx.x * 256 + threadIdx.x;
    if (idx >= Nn) return;
    int rs = incl[idx] - deg[idx] + bsums[blockIdx.x];
    rowstart[idx] = rs;
    cursor[idx] = rs;
}
__global__ __launch_bounds__(256) void csr_fill(const int* __restrict__ ei, int* __restrict__ cursor,
                                                int* __restrict__ csrc, int E, int Nn) {
    int i = blockIdx.x * 256 + threadIdx.x;
    if (i >= E + Nn) return;
    int s, d;
    if (i < E) { s = ei[i]; d = ei[E + i]; } else { s = d = i - E; }
    int pos = atomicAdd(&cursor[d], 1);
    csrc[pos] = s;
}

// ---------- fused segment softmax: logits -> max -> exp/sum -> alpha in wse ----------
template<int H>
__global__ __launch_bounds__(256) void seg_softmax(
    const int* __restrict__ rowstart, const int* __restrict__ deg,
    const int* __restrict__ csrc, const float* __restrict__ es,
    const float* __restrict__ ed, float* __restrict__ wse, int Nn)
{
    int d = (blockIdx.x * 256 + threadIdx.x) >> 6;
    int lane = threadIdx.x & 63;
    if (d >= Nn) return;
    constexpr int S = 64 / H;
    int head = lane & (H - 1);
    int slot = lane / H;
    int st = rowstart[d], dg = deg[d];
    float edv = ed[d * H + head];
    float m = -1e30f;
    for (int j = slot; j < dg; j += S) {
        float l = es[csrc[st + j] * H + head] + edv;
        l = l > 0.f ? l : 0.2f * l;
        wse[(size_t)(st + j) * H + head] = l;
        m = fmaxf(m, l);
    }
    #pragma unroll
    for (int o = H; o < 64; o <<= 1) m = fmaxf(m, __shfl_xor(m, o));
    float z = 0.f;
    for (int j = slot; j < dg; j += S) {
        float e = expf(wse[(size_t)(st + j) * H + head] - m);
        wse[(size_t)(st + j) * H + head] = e;
        z += e;
    }
    #pragma unroll
    for (int o = H; o < 64; o <<= 1) z += __shfl_xor(z, o);
    float rz = 1.f / (z + 1e-16f);
    for (int j = slot; j < dg; j += S)
        wse[(size_t)(st + j) * H + head] *= rz;
}

// ---------- fused gather + bias + LN + ELU (+resid): one block per dst ----------
// H=4: 128 threads x 8 ch (f16x8 16B loads); H=1: 64 threads x 4 ch.
template<int H>
__global__ __launch_bounds__(H == 4 ? 128 : 64) void gat_gather_ln(
    const int* __restrict__ rowstart, const int* __restrict__ deg,
    const int* __restrict__ csrc, const float* __restrict__ wse,
    const _Float16* __restrict__ h,
    const float* __restrict__ bias, const float* __restrict__ gam,
    const float* __restrict__ bet, const float* resid,
    float* xout, _Float16* xout16)
{
    constexpr int T = (H == 4) ? 128 : 64;
    constexpr int CPT = (H == 4) ? 8 : 4;      // channels per thread
    constexpr int NW = T / 64;
    constexpr int HC = H * 256;
    typedef typename f16vec_t<CPT>::type hvec;
    int d = blockIdx.x;
    int t = threadIdx.x;
    int lane = t & 63, wave = t >> 6;
    int ch0 = t * CPT;
    int head2 = ch0 >> 8;
    int st = rowstart[d], dg = deg[d];
    const _Float16* hb = h + ch0;

    float acc[CPT];
    #pragma unroll
    for (int k = 0; k < CPT; k++) acc[k] = 0.f;

    int j = 0;
    for (; j + 4 <= dg; j += 4) {              // four 16B loads in flight
        int s0 = csrc[st + j], s1 = csrc[st + j + 1];
        int s2 = csrc[st + j + 2], s3 = csrc[st + j + 3];
        float w0 = wse[(size_t)(st + j) * H + head2];
        float w1 = wse[(size_t)(st + j + 1) * H + head2];
        float w2 = wse[(size_t)(st + j + 2) * H + head2];
        float w3 = wse[(size_t)(st + j + 3) * H + head2];
        hvec v0 = *(const hvec*)(hb + (size_t)s0 * HC);
        hvec v1 = *(const hvec*)(hb + (size_t)s1 * HC);
        hvec v2 = *(const hvec*)(hb + (size_t)s2 * HC);
        hvec v3 = *(const hvec*)(hb + (size_t)s3 * HC);
        #pragma unroll
        for (int k = 0; k < CPT; k++)
            acc[k] += w0 * (float)v0[k] + w1 * (float)v1[k]
                    + w2 * (float)v2[k] + w3 * (float)v3[k];
    }
    for (; j < dg; j++) {
        int s0 = csrc[st + j];
        float w0 = wse[(size_t)(st + j) * H + head2];
        hvec v0 = *(const hvec*)(hb + (size_t)s0 * HC);
        #pragma unroll
        for (int k = 0; k < CPT; k++) acc[k] += w0 * (float)v0[k];
    }

    #pragma unroll
    for (int k = 0; k < CPT; k++) acc[k] += bias[ch0 + k];

    // layernorm over the block-owned row
    __shared__ float sm[NW > 1 ? NW : 1];
    float sum = 0.f;
    #pragma unroll
    for (int k = 0; k < CPT; k++) sum += acc[k];
    #pragma unroll
    for (int o = 32; o; o >>= 1) sum += __shfl_down(sum, o);
    float tot;
    if (NW > 1) {
        if (lane == 0) sm[wave] = sum;
        __syncthreads();
        tot = 0.f;
        #pragma unroll
        for (int w2 = 0; w2 < NW; w2++) tot += sm[w2];
    } else {
        tot = __shfl(sum, 0);
    }
    float mean = tot / (float)HC;
    float sq = 0.f;
    #pragma unroll
    for (int k = 0; k < CPT; k++) { float dd = acc[k] - mean; sq = fmaf(dd, dd, sq); }
    #pragma unroll
    for (int o = 32; o; o >>= 1) sq += __shfl_down(sq, o);
    if (NW > 1) {
        __syncthreads();
        if (lane == 0) sm[wave] = sq;
        __syncthreads();
        tot = 0.f;
        #pragma unroll
        for (int w2 = 0; w2 < NW; w2++) tot += sm[w2];
    } else {
        tot = __shfl(sq, 0);
    }
    float rstd = rsqrtf(tot / (float)HC + 1e-5f);

    float y[CPT];
    #pragma unroll
    for (int k = 0; k < CPT; k++) {
        float v = (acc[k] - mean) * rstd * gam[ch0 + k] + bet[ch0 + k];
        y[k] = v > 0.f ? v : (expf(v) - 1.f);
    }
    if (resid) {
        #pragma unroll
        for (int q = 0; q < CPT / 4; q++) {
            float4 r = ((const float4*)resid)[(size_t)d * (HC / 4) + t * (CPT / 4) + q];
            y[q * 4 + 0] += r.x; y[q * 4 + 1] += r.y; y[q * 4 + 2] += r.z; y[q * 4 + 3] += r.w;
        }
    }
    #pragma unroll
    for (int q = 0; q < CPT / 4; q++)
        ((float4*)xout)[(size_t)d * (HC / 4) + t * (CPT / 4) + q] =
            make_float4(y[q * 4 + 0], y[q * 4 + 1], y[q * 4 + 2], y[q * 4 + 3]);
    if (xout16) {
        hvec o;
        #pragma unroll
        for (int k = 0; k < CPT; k++) o[k] = (_Float16)y[k];
        *(hvec*)(xout16 + (size_t)d * HC + ch0) = o;
    }
}

// ---------- graph pooling: 16 nodes per block, register pre-reduce ----------
__global__ __launch_bounds__(256) void pool_kernel(
    const float* __restrict__ x3, const int* __restrict__ batch,
    float* __restrict__ ps, unsigned* __restrict__ pm, int* __restrict__ cnt, int Nn)
{
    int c = threadIdx.x;
    int n0 = blockIdx.x * 16;
    int end = n0 + 16; if (end > Nn) end = Nn;
    if (n0 >= Nn) return;
    int curg = batch[n0];
    float s = 0.f, m = -1e30f; int k = 0;
    for (int n = n0; n < end; n++) {
        int g = batch[n];
        if (g != curg) {
            atomicAdd(&ps[curg * 256 + c], s);
            atomicMax(&pm[curg * 256 + c], encf(m));
            if (c == 0) atomicAdd(&cnt[curg], k);
            s = 0.f; m = -1e30f; k = 0; curg = g;
        }
        float v = x3[(size_t)n * 256 + c];
        s += v; m = fmaxf(m, v); k++;
    }
    atomicAdd(&ps[curg * 256 + c], s);
    atomicMax(&pm[curg * 256 + c], encf(m));
    if (c == 0) atomicAdd(&cnt[curg], k);
}

// ---------- classifier: [mean|max|sum] @ W1 -> relu -> @ W2 ----------
__global__ __launch_bounds__(128) void classifier_kernel(
    const float* __restrict__ ps, const unsigned* __restrict__ pm, const int* __restrict__ cnt,
    const float* __restrict__ w1, const float* __restrict__ b1,
    const float* __restrict__ w2, const float* __restrict__ b2, float* __restrict__ out)
{
    int g = blockIdx.x;
    int tid = threadIdx.x; // 128
    __shared__ float pooled[768];
    __shared__ float red[2];
    float c = (float)cnt[g];
    if (c < 1.f) c = 1.f;
    for (int i = tid; i < 256; i += 128) {
        float s = ps[g * 256 + i];
        pooled[i] = s / c;
        pooled[256 + i] = decf(pm[g * 256 + i]);
        pooled[512 + i] = s;
    }
    __syncthreads();
    float acc = b1[tid];
    for (int k = 0; k < 768; k++) acc = fmaf(pooled[k], w1[k * 128 + tid], acc);
    acc = fmaxf(acc, 0.f);
    float v = acc * w2[tid];
    #pragma unroll
    for (int o = 32; o; o >>= 1) v += __shfl_down(v, o);
    if ((tid & 63) == 0) red[tid >> 6] = v;
    __syncthreads();
    if (tid == 0) out[g] = red[0] + red[1] + b2[0];
}

// ---------- launcher ----------
extern "C" void kernel_launch(void* const* d_in, const int* in_sizes, int n_in,
                              void* d_out, int out_size, void* d_ws, size_t ws_size,
                              hipStream_t stream)
{
    const float* x      = (const float*)d_in[0];
    const int*   ei     = (const int*)d_in[1];
    const int*   batch  = (const int*)d_in[2];
    const float* proj_w = (const float*)d_in[3];
    const float* proj_b = (const float*)d_in[4];
    const float* gat1_w = (const float*)d_in[5];
    const float* att1_s = (const float*)d_in[6];
    const float* att1_d = (const float*)d_in[7];
    const float* gat1_b = (const float*)d_in[8];
    const float* ln1_g  = (const float*)d_in[9];
    const float* ln1_b  = (const float*)d_in[10];
    const float* gat2_w = (const float*)d_in[11];
    const float* att2_s = (const float*)d_in[12];
    const float* att2_d = (const float*)d_in[13];
    const float* gat2_b = (const float*)d_in[14];
    const float* ln2_g  = (const float*)d_in[15];
    const float* ln2_b  = (const float*)d_in[16];
    const float* gat3_w = (const float*)d_in[17];
    const float* att3_s = (const float*)d_in[18];
    const float* att3_d = (const float*)d_in[19];
    const float* gat3_b = (const float*)d_in[20];
    const float* ln3_g  = (const float*)d_in[21];
    const float* ln3_b  = (const float*)d_in[22];
    const float* cls1_w = (const float*)d_in[23];
    const float* cls1_b = (const float*)d_in[24];
    const float* cls2_w = (const float*)d_in[25];
    const float* cls2_b = (const float*)d_in[26];

    int Nn = in_sizes[0] / 768;
    int E  = in_sizes[1] / 2;
    int Gg = out_size;           // 32
    int Etot = E + Nn;
    int nb  = (Nn + 255) / 256;

    // ---- workspace layout (aligned to 256 B) ----
    char* w = (char*)d_ws;
    size_t off = 0;
    auto alloc = [&](size_t bytes) -> char* {
        char* r = w + off;
        off += (bytes + 255) & ~(size_t)255;
        return r;
    };
    size_t NB16 = (size_t)Nn * 1024 * sizeof(_Float16);
    size_t NB32 = (size_t)Nn * 1024 * sizeof(float);
    _Float16* P = (_Float16*)alloc(NB16);     // x16 -> h1 -> h2 -> h3
    _Float16* Q = (_Float16*)alloc(NB16);     // hproj16 -> x1_16 -> x2_16
    float*  X = (float*)alloc(NB32);          // x1/x2 fp32 resid chain -> x3
    _Float16* projT = (_Float16*)alloc((size_t)768 * 768 * 2);
    _Float16* g1T   = (_Float16*)alloc((size_t)1024 * 768 * 2);
    _Float16* g2T   = (_Float16*)alloc((size_t)1024 * 1024 * 2);
    _Float16* g3T   = (_Float16*)alloc((size_t)256 * 1024 * 2);
    float*    es    = (float*)alloc((size_t)Nn * 4 * 4);
    float*    ed_   = (float*)alloc((size_t)Nn * 4 * 4);
    int*      deg   = (int*)alloc((size_t)Nn * 4);
    int*      incl  = (int*)alloc((size_t)Nn * 4);
    int*      rowst = (int*)alloc((size_t)Nn * 4);
    int*      curs  = (int*)alloc((size_t)Nn * 4);
    int*      bsums = (int*)alloc((size_t)nb * 4);
    int*      csrc  = (int*)alloc((size_t)Etot * 4);
    float*    wse   = (float*)alloc((size_t)Etot * 4 * 4);
    float*    ps    = (float*)alloc((size_t)Gg * 256 * 4);
    unsigned* pm    = (unsigned*)alloc((size_t)Gg * 256 * 4);
    int*      cnt   = (int*)alloc(256);

    dim3 blk(256);

    // ---- weight transpose+convert ----
    wt_kernel<<<dim3(768 / 32, 768 / 32), blk, 0, stream>>>(proj_w, projT, 768, 768);
    wt_kernel<<<dim3(1024 / 32, 768 / 32), blk, 0, stream>>>(gat1_w, g1T, 768, 1024);
    wt_kernel<<<dim3(1024 / 32, 1024 / 32), blk, 0, stream>>>(gat2_w, g2T, 1024, 1024);
    wt_kernel<<<dim3(256 / 32, 1024 / 32), blk, 0, stream>>>(gat3_w, g3T, 1024, 256);

    // ---- x -> fp16 ----
    {
        size_t n4 = (size_t)Nn * 768 / 4;
        cvt_f16_kernel<<<dim3((unsigned)((n4 + 255) / 256)), blk, 0, stream>>>(x, P, n4);
    }

    // ---- CSR by dst ----
    csr_init<<<dim3(nb), blk, 0, stream>>>(deg, Nn);
    csr_count<<<dim3((E + 255) / 256), blk, 0, stream>>>(ei, deg, E);
    scan1<<<dim3(nb), blk, 0, stream>>>(deg, incl, bsums, Nn);
    scan2<<<dim3(1), dim3(64), 0, stream>>>(bsums, nb);
    scan3<<<dim3(nb), blk, 0, stream>>>(incl, deg, bsums, rowst, curs, Nn);
    csr_fill<<<dim3((Etot + 255) / 256), blk, 0, stream>>>(ei, curs, csrc, E, Nn);

    int mg = (Nn + 127) / 128;

    // proj: hproj16 = elu(x16 @ projW + b) -> Q   (no score fusion)
    gemm_f16<<<dim3(768 / 128, mg), blk, 0, stream>>>(P, projT, proj_b, Q,
                                                      nullptr, nullptr, nullptr, nullptr,
                                                      Nn, 768, 768, 1, 0);

    auto run_gat = [&](const _Float16* xin16, const _Float16* WT, const float* as_, const float* ad_,
                       const float* gb, const float* lg, const float* lb, const float* resid,
                       _Float16* hbuf, float* xout, _Float16* xout16,
                       int K, int H, int C) {
        int HC = H * C;
        hipMemsetAsync(es, 0, (size_t)Nn * H * 4, stream);
        hipMemsetAsync(ed_, 0, (size_t)Nn * H * 4, stream);
        gemm_f16<<<dim3(HC / 128, mg), blk, 0, stream>>>(xin16, WT, nullptr, hbuf,
                                                         as_, ad_, es, ed_,
                                                         Nn, K, HC, 0, H);
        if (H == 4) {
            seg_softmax<4><<<dim3((Nn + 3) / 4), blk, 0, stream>>>(rowst, deg, csrc, es, ed_, wse, Nn);
            gat_gather_ln<4><<<dim3(Nn), dim3(128), 0, stream>>>(rowst, deg, csrc, wse, hbuf,
                                                                 gb, lg, lb, resid, xout, xout16);
        } else {
            seg_softmax<1><<<dim3((Nn + 3) / 4), blk, 0, stream>>>(rowst, deg, csrc, es, ed_, wse, Nn);
            gat_gather_ln<1><<<dim3(Nn), dim3(64), 0, stream>>>(rowst, deg, csrc, wse, hbuf,
                                                                gb, lg, lb, resid, xout, xout16);
        }
    };

    // layer 1: 768 -> 4x256. A=Q(hproj) -> h1 in P; x1 -> X (fp32) + Q (fp16)
    run_gat(Q, g1T, att1_s, att1_d, gat1_b, ln1_g, ln1_b, nullptr, P, X, Q, 768, 4, 256);
    // layer 2: 1024 -> 4x256, resid x1 (X). A=Q(x1_16) -> h2 in P; x2 -> X in place + Q
    run_gat(Q, g2T, att2_s, att2_d, gat2_b, ln2_g, ln2_b, X, P, X, Q, 1024, 4, 256);
    // layer 3: 1024 -> 256 (1 head). A=Q(x2_16) -> h3 in P; x3 -> X fp32 only
    run_gat(Q, g3T, att3_s, att3_d, gat3_b, ln3_g, ln3_b, nullptr, P, X, nullptr, 1024, 1, 256);

    // pooling + classifier
    hipMemsetAsync(ps, 0, (size_t)Gg * 256 * 4, stream);
    hipMemsetAsync(pm, 0, (size_t)Gg * 256 * 4, stream);
    hipMemsetAsync(cnt, 0, (size_t)Gg * 4, stream);
    pool_kernel<<<dim3((Nn + 15) / 16), blk, 0, stream>>>(X, batch, ps, pm, cnt, Nn);
    classifier_kernel<<<dim3(Gg), dim3(128), 0, stream>>>(ps, pm, cnt, cls1_w, cls1_b, cls2_w, cls2_b, (float*)d_out);
}

// Round 10
// 783.936 us; speedup vs baseline: 1.0796x; 1.0796x over previous
//
#include <hip/hip_runtime.h>
#include <math.h>

typedef float floatx4 __attribute__((ext_vector_type(4)));
typedef _Float16 f16x8 __attribute__((ext_vector_type(8)));
typedef _Float16 f16x4 __attribute__((ext_vector_type(4)));

template<int N> struct f16vec_t;
template<> struct f16vec_t<4> { typedef f16x4 type; };
template<> struct f16vec_t<8> { typedef f16x8 type; };

// ---------- helpers ----------
__device__ __forceinline__ unsigned encf(float f) {
    unsigned u = __float_as_uint(f);
    return (u & 0x80000000u) ? ~u : (u | 0x80000000u);
}
__device__ __forceinline__ float decf(unsigned u) {
    u = (u & 0x80000000u) ? (u & 0x7FFFFFFFu) : ~u;
    return __uint_as_float(u);
}
__device__ __forceinline__ float fexp(float x) { return __expf(x); }
// async global->LDS, 16 B per lane; LDS dst = wave-uniform base + lane*16
__device__ __forceinline__ void glds16(const void* g, void* l) {
    __builtin_amdgcn_global_load_lds(
        (const __attribute__((address_space(1))) unsigned int*)g,
        (__attribute__((address_space(3))) unsigned int*)l, 16, 0, 0);
}

// ---------- fp32 -> fp16 convert (vec4) ----------
__global__ __launch_bounds__(256) void cvt_f16_kernel(
    const float* __restrict__ in, _Float16* __restrict__ out, size_t n4)
{
    size_t i = (size_t)blockIdx.x * 256 + threadIdx.x;
    if (i >= n4) return;
    float4 v = ((const float4*)in)[i];
    f16x4 o;
    o[0] = (_Float16)v.x; o[1] = (_Float16)v.y; o[2] = (_Float16)v.z; o[3] = (_Float16)v.w;
    ((f16x4*)out)[i] = o;
}

// ---------- batched weight transpose+convert: 4 matrices in one launch ----------
// job dims hardcoded to this problem: (768x768),(768x1024),(1024x1024),(1024x256)
__global__ __launch_bounds__(256) void wt_all_kernel(
    const float* __restrict__ w0, _Float16* __restrict__ o0,
    const float* __restrict__ w1, _Float16* __restrict__ o1,
    const float* __restrict__ w2, _Float16* __restrict__ o2,
    const float* __restrict__ w3, _Float16* __restrict__ o3)
{
    int b = blockIdx.x;
    const float* w; _Float16* wt; int K, N, lb;
    if (b < 576)       { w = w0; wt = o0; K = 768;  N = 768;  lb = b; }
    else if (b < 1344) { w = w1; wt = o1; K = 768;  N = 1024; lb = b - 576; }
    else if (b < 2368) { w = w2; wt = o2; K = 1024; N = 1024; lb = b - 1344; }
    else               { w = w3; wt = o3; K = 1024; N = 256;  lb = b - 2368; }
    int ntx = N / 32;
    int bx = (lb % ntx) * 32, by = (lb / ntx) * 32;  // bx: n, by: k
    __shared__ float t[32][33];
    int tx = threadIdx.x & 31, ty = threadIdx.x >> 5; // 32x8
    for (int r = ty; r < 32; r += 8)
        t[r][tx] = w[(size_t)(by + r) * N + bx + tx];
    __syncthreads();
    for (int r = ty; r < 32; r += 8)
        wt[(size_t)(bx + r) * K + by + tx] = (_Float16)t[tx][r];
}

// ---------- fp16 MFMA GEMM, double-buffered global_load_lds staging ----------
__global__ __launch_bounds__(256) void gemm_f16(
    const _Float16* __restrict__ A, const _Float16* __restrict__ BT,
    const float* __restrict__ bias, _Float16* __restrict__ C,
    int M, int K, int N, int act)
{
    __shared__ _Float16 Al[2][128 * 32];
    __shared__ _Float16 Bl[2][128 * 32];
    int tid = threadIdx.x;
    int lane = tid & 63, wave = tid >> 6;
    int row0 = blockIdx.y * 128, col0 = blockIdx.x * 128;
    int wm = (wave >> 1) * 64, wn = (wave & 1) * 64;
    int l15 = lane & 15, quad = lane >> 4;

    int rg0 = wave * 2, rg1 = rg0 + 1;
    int srow0 = rg0 * 16 + (lane >> 2);
    int srow1 = rg1 * 16 + (lane >> 2);
    int scol = (lane & 3) * 8;
    int arow0 = row0 + srow0; if (arow0 > M - 1) arow0 = M - 1;
    int arow1 = row0 + srow1; if (arow1 > M - 1) arow1 = M - 1;
    const _Float16* gA0 = A + (size_t)arow0 * K + scol;
    const _Float16* gA1 = A + (size_t)arow1 * K + scol;
    const _Float16* gB0 = BT + (size_t)(col0 + srow0) * K + scol;
    const _Float16* gB1 = BT + (size_t)(col0 + srow1) * K + scol;

    floatx4 acc[4][4] = {};

    glds16(gA0, &Al[0][rg0 * 512]);
    glds16(gA1, &Al[0][rg1 * 512]);
    glds16(gB0, &Bl[0][rg0 * 512]);
    glds16(gB1, &Bl[0][rg1 * 512]);

    int nk = K >> 5;
    for (int it = 0; it < nk; it++) {
        int cur = it & 1, nxt = cur ^ 1;
        __syncthreads();
        if (it + 1 < nk) {
            int k1 = (it + 1) << 5;
            glds16(gA0 + k1, &Al[nxt][rg0 * 512]);
            glds16(gA1 + k1, &Al[nxt][rg1 * 512]);
            glds16(gB0 + k1, &Bl[nxt][rg0 * 512]);
            glds16(gB1 + k1, &Bl[nxt][rg1 * 512]);
        }
        f16x8 af[4], bfr[4];
        #pragma unroll
        for (int i = 0; i < 4; i++) {
            af[i]  = *(const f16x8*)&Al[cur][(wm + i * 16 + l15) * 32 + quad * 8];
            bfr[i] = *(const f16x8*)&Bl[cur][(wn + i * 16 + l15) * 32 + quad * 8];
        }
        #pragma unroll
        for (int i = 0; i < 4; i++)
            #pragma unroll
            for (int j = 0; j < 4; j++)
                acc[i][j] = __builtin_amdgcn_mfma_f32_16x16x32_f16(af[i], bfr[j], acc[i][j], 0, 0, 0);
    }

    // epilogue: D row = quad*4+reg, col = l15
    #pragma unroll
    for (int i = 0; i < 4; i++) {
        #pragma unroll
        for (int v = 0; v < 4; v++) {
            int gr = row0 + wm + i * 16 + quad * 4 + v;
            if (gr >= M) continue;
            #pragma unroll
            for (int j = 0; j < 4; j++) {
                int gc = col0 + wn + j * 16 + l15;
                float val = acc[i][j][v];
                if (bias) val += bias[gc];
                if (act) val = val > 0.f ? val : (fexp(val) - 1.f);
                C[(size_t)gr * N + gc] = (_Float16)val;
            }
        }
    }
}

// ---------- per-(node,head) attention scores from fp16 h ----------
__global__ __launch_bounds__(256) void attn_scores_kernel(
    const _Float16* __restrict__ h, const float* __restrict__ asrc, const float* __restrict__ adst,
    float* __restrict__ es, float* __restrict__ ed, int Nn, int H)
{
    int wid = (blockIdx.x * 256 + threadIdx.x) >> 6;
    int lane = threadIdx.x & 63;
    if (wid >= Nn * H) return;
    int node = wid / H, hh = wid % H;
    const _Float16* hp = h + (size_t)node * H * 256 + hh * 256 + lane * 4;
    f16x4 v = *(const f16x4*)hp;
    float ss = 0.f, sd = 0.f;
    #pragma unroll
    for (int j = 0; j < 4; j++) {
        float f = (float)v[j];
        ss = fmaf(f, asrc[hh * 256 + lane * 4 + j], ss);
        sd = fmaf(f, adst[hh * 256 + lane * 4 + j], sd);
    }
    #pragma unroll
    for (int o = 32; o; o >>= 1) { ss += __shfl_down(ss, o); sd += __shfl_down(sd, o); }
    if (lane == 0) { es[wid] = ss; ed[wid] = sd; }
}

// ---------- CSR build ----------
__global__ __launch_bounds__(256) void csr_init(int* __restrict__ deg, int Nn) {
    int i = blockIdx.x * 256 + threadIdx.x;
    if (i < Nn) deg[i] = 1;               // self-loop
}
__global__ __launch_bounds__(256) void csr_count(const int* __restrict__ ei, int* __restrict__ deg, int E) {
    int i = blockIdx.x * 256 + threadIdx.x;
    if (i < E) atomicAdd(&deg[ei[E + i]], 1);
}
__global__ __launch_bounds__(256) void scan1(const int* __restrict__ deg, int* __restrict__ incl,
                                             int* __restrict__ bsums, int Nn) {
    __shared__ int sd[256];
    int idx = blockIdx.x * 256 + threadIdx.x;
    sd[threadIdx.x] = (idx < Nn) ? deg[idx] : 0;
    __syncthreads();
    for (int o = 1; o < 256; o <<= 1) {
        int x = (threadIdx.x >= (unsigned)o) ? sd[threadIdx.x - o] : 0;
        __syncthreads();
        sd[threadIdx.x] += x;
        __syncthreads();
    }
    if (idx < Nn) incl[idx] = sd[threadIdx.x];
    if (threadIdx.x == 255) bsums[blockIdx.x] = sd[255];
}
__global__ void scan2(int* __restrict__ bsums, int nb) {
    if (blockIdx.x == 0 && threadIdx.x == 0) {
        int run = 0;
        for (int i = 0; i < nb; i++) { int v = bsums[i]; bsums[i] = run; run += v; }
    }
}
__global__ __launch_bounds__(256) void scan3(const int* __restrict__ incl, const int* __restrict__ deg,
                                             const int* __restrict__ bsums, int* __restrict__ rowstart,
                                             int* __restrict__ cursor, int Nn) {
    int idx = blockIdx.x * 256 + threadIdx.x;
    if (idx >= Nn) return;
    int rs = incl[idx] - deg[idx] + bsums[blockIdx.x];
    rowstart[idx] = rs;
    cursor[idx] = rs;
}
__global__ __launch_bounds__(256) void csr_fill(const int* __restrict__ ei, int* __restrict__ cursor,
                                                int* __restrict__ csrc, int E, int Nn) {
    int i = blockIdx.x * 256 + threadIdx.x;
    if (i >= E + Nn) return;
    int s, d;
    if (i < E) { s = ei[i]; d = ei[E + i]; } else { s = d = i - E; }
    int pos = atomicAdd(&cursor[d], 1);
    csrc[pos] = s;
}

// ---------- fused segment softmax: logits -> max -> exp/sum -> alpha in wse ----------
template<int H>
__global__ __launch_bounds__(256) void seg_softmax(
    const int* __restrict__ rowstart, const int* __restrict__ deg,
    const int* __restrict__ csrc, const float* __restrict__ es,
    const float* __restrict__ ed, float* __restrict__ wse, int Nn)
{
    int d = (blockIdx.x * 256 + threadIdx.x) >> 6;
    int lane = threadIdx.x & 63;
    if (d >= Nn) return;
    constexpr int S = 64 / H;
    int head = lane & (H - 1);
    int slot = lane / H;
    int st = rowstart[d], dg = deg[d];
    float edv = ed[d * H + head];
    float m = -1e30f;
    for (int j = slot; j < dg; j += S) {
        float l = es[csrc[st + j] * H + head] + edv;
        l = l > 0.f ? l : 0.2f * l;
        wse[(size_t)(st + j) * H + head] = l;
        m = fmaxf(m, l);
    }
    #pragma unroll
    for (int o = H; o < 64; o <<= 1) m = fmaxf(m, __shfl_xor(m, o));
    float z = 0.f;
    for (int j = slot; j < dg; j += S) {
        float e = fexp(wse[(size_t)(st + j) * H + head] - m);
        wse[(size_t)(st + j) * H + head] = e;
        z += e;
    }
    #pragma unroll
    for (int o = H; o < 64; o <<= 1) z += __shfl_xor(z, o);
    float rz = 1.f / (z + 1e-16f);
    for (int j = slot; j < dg; j += S)
        wse[(size_t)(st + j) * H + head] *= rz;
}

// ---------- fused gather + bias + LN + ELU (+resid): one block per dst ----------
// H=4: 128 threads x 8 ch (f16x8 16B loads); H=1: 64 threads x 4 ch.
template<int H>
__global__ __launch_bounds__(H == 4 ? 128 : 64) void gat_gather_ln(
    const int* __restrict__ rowstart, const int* __restrict__ deg,
    const int* __restrict__ csrc, const float* __restrict__ wse,
    const _Float16* __restrict__ h,
    const float* __restrict__ bias, const float* __restrict__ gam,
    const float* __restrict__ bet, const float* resid,
    float* xout, _Float16* xout16)
{
    constexpr int T = (H == 4) ? 128 : 64;
    constexpr int CPT = (H == 4) ? 8 : 4;      // channels per thread
    constexpr int NW = T / 64;
    constexpr int HC = H * 256;
    typedef typename f16vec_t<CPT>::type hvec;
    int d = blockIdx.x;
    int t = threadIdx.x;
    int lane = t & 63, wave = t >> 6;
    int ch0 = t * CPT;
    int head2 = ch0 >> 8;
    int st = rowstart[d], dg = deg[d];
    const _Float16* hb = h + ch0;

    float acc[CPT];
    #pragma unroll
    for (int k = 0; k < CPT; k++) acc[k] = 0.f;

    int j = 0;
    for (; j + 4 <= dg; j += 4) {              // four 16B loads in flight
        int s0 = csrc[st + j], s1 = csrc[st + j + 1];
        int s2 = csrc[st + j + 2], s3 = csrc[st + j + 3];
        float w0 = wse[(size_t)(st + j) * H + head2];
        float w1 = wse[(size_t)(st + j + 1) * H + head2];
        float w2 = wse[(size_t)(st + j + 2) * H + head2];
        float w3 = wse[(size_t)(st + j + 3) * H + head2];
        hvec v0 = *(const hvec*)(hb + (size_t)s0 * HC);
        hvec v1 = *(const hvec*)(hb + (size_t)s1 * HC);
        hvec v2 = *(const hvec*)(hb + (size_t)s2 * HC);
        hvec v3 = *(const hvec*)(hb + (size_t)s3 * HC);
        #pragma unroll
        for (int k = 0; k < CPT; k++)
            acc[k] += w0 * (float)v0[k] + w1 * (float)v1[k]
                    + w2 * (float)v2[k] + w3 * (float)v3[k];
    }
    for (; j < dg; j++) {
        int s0 = csrc[st + j];
        float w0 = wse[(size_t)(st + j) * H + head2];
        hvec v0 = *(const hvec*)(hb + (size_t)s0 * HC);
        #pragma unroll
        for (int k = 0; k < CPT; k++) acc[k] += w0 * (float)v0[k];
    }

    #pragma unroll
    for (int k = 0; k < CPT; k++) acc[k] += bias[ch0 + k];

    // layernorm over the block-owned row
    __shared__ float sm[NW > 1 ? NW : 1];
    float sum = 0.f;
    #pragma unroll
    for (int k = 0; k < CPT; k++) sum += acc[k];
    #pragma unroll
    for (int o = 32; o; o >>= 1) sum += __shfl_down(sum, o);
    float tot;
    if (NW > 1) {
        if (lane == 0) sm[wave] = sum;
        __syncthreads();
        tot = 0.f;
        #pragma unroll
        for (int w2 = 0; w2 < NW; w2++) tot += sm[w2];
    } else {
        tot = __shfl(sum, 0);
    }
    float mean = tot / (float)HC;
    float sq = 0.f;
    #pragma unroll
    for (int k = 0; k < CPT; k++) { float dd = acc[k] - mean; sq = fmaf(dd, dd, sq); }
    #pragma unroll
    for (int o = 32; o; o >>= 1) sq += __shfl_down(sq, o);
    if (NW > 1) {
        __syncthreads();
        if (lane == 0) sm[wave] = sq;
        __syncthreads();
        tot = 0.f;
        #pragma unroll
        for (int w2 = 0; w2 < NW; w2++) tot += sm[w2];
    } else {
        tot = __shfl(sq, 0);
    }
    float rstd = rsqrtf(tot / (float)HC + 1e-5f);

    float y[CPT];
    #pragma unroll
    for (int k = 0; k < CPT; k++) {
        float v = (acc[k] - mean) * rstd * gam[ch0 + k] + bet[ch0 + k];
        y[k] = v > 0.f ? v : (fexp(v) - 1.f);
    }
    if (resid) {
        #pragma unroll
        for (int q = 0; q < CPT / 4; q++) {
            float4 r = ((const float4*)resid)[(size_t)d * (HC / 4) + t * (CPT / 4) + q];
            y[q * 4 + 0] += r.x; y[q * 4 + 1] += r.y; y[q * 4 + 2] += r.z; y[q * 4 + 3] += r.w;
        }
    }
    #pragma unroll
    for (int q = 0; q < CPT / 4; q++)
        ((float4*)xout)[(size_t)d * (HC / 4) + t * (CPT / 4) + q] =
            make_float4(y[q * 4 + 0], y[q * 4 + 1], y[q * 4 + 2], y[q * 4 + 3]);
    if (xout16) {
        hvec o;
        #pragma unroll
        for (int k = 0; k < CPT; k++) o[k] = (_Float16)y[k];
        *(hvec*)(xout16 + (size_t)d * HC + ch0) = o;
    }
}

// ---------- graph pooling: 16 nodes per block, register pre-reduce ----------
__global__ __launch_bounds__(256) void pool_kernel(
    const float* __restrict__ x3, const int* __restrict__ batch,
    float* __restrict__ ps, unsigned* __restrict__ pm, int* __restrict__ cnt, int Nn)
{
    int c = threadIdx.x;
    int n0 = blockIdx.x * 16;
    int end = n0 + 16; if (end > Nn) end = Nn;
    if (n0 >= Nn) return;
    int curg = batch[n0];
    float s = 0.f, m = -1e30f; int k = 0;
    for (int n = n0; n < end; n++) {
        int g = batch[n];
        if (g != curg) {
            atomicAdd(&ps[curg * 256 + c], s);
            atomicMax(&pm[curg * 256 + c], encf(m));
            if (c == 0) atomicAdd(&cnt[curg], k);
            s = 0.f; m = -1e30f; k = 0; curg = g;
        }
        float v = x3[(size_t)n * 256 + c];
        s += v; m = fmaxf(m, v); k++;
    }
    atomicAdd(&ps[curg * 256 + c], s);
    atomicMax(&pm[curg * 256 + c], encf(m));
    if (c == 0) atomicAdd(&cnt[curg], k);
}

// ---------- classifier: [mean|max|sum] @ W1 -> relu -> @ W2 ----------
__global__ __launch_bounds__(128) void classifier_kernel(
    const float* __restrict__ ps, const unsigned* __restrict__ pm, const int* __restrict__ cnt,
    const float* __restrict__ w1, const float* __restrict__ b1,
    const float* __restrict__ w2, const float* __restrict__ b2, float* __restrict__ out)
{
    int g = blockIdx.x;
    int tid = threadIdx.x; // 128
    __shared__ float pooled[768];
    __shared__ float red[2];
    float c = (float)cnt[g];
    if (c < 1.f) c = 1.f;
    for (int i = tid; i < 256; i += 128) {
        float s = ps[g * 256 + i];
        pooled[i] = s / c;
        pooled[256 + i] = decf(pm[g * 256 + i]);
        pooled[512 + i] = s;
    }
    __syncthreads();
    float acc = b1[tid];
    for (int k = 0; k < 768; k++) acc = fmaf(pooled[k], w1[k * 128 + tid], acc);
    acc = fmaxf(acc, 0.f);
    float v = acc * w2[tid];
    #pragma unroll
    for (int o = 32; o; o >>= 1) v += __shfl_down(v, o);
    if ((tid & 63) == 0) red[tid >> 6] = v;
    __syncthreads();
    if (tid == 0) out[g] = red[0] + red[1] + b2[0];
}

// ---------- launcher ----------
extern "C" void kernel_launch(void* const* d_in, const int* in_sizes, int n_in,
                              void* d_out, int out_size, void* d_ws, size_t ws_size,
                              hipStream_t stream)
{
    const float* x      = (const float*)d_in[0];
    const int*   ei     = (const int*)d_in[1];
    const int*   batch  = (const int*)d_in[2];
    const float* proj_w = (const float*)d_in[3];
    const float* proj_b = (const float*)d_in[4];
    const float* gat1_w = (const float*)d_in[5];
    const float* att1_s = (const float*)d_in[6];
    const float* att1_d = (const float*)d_in[7];
    const float* gat1_b = (const float*)d_in[8];
    const float* ln1_g  = (const float*)d_in[9];
    const float* ln1_b  = (const float*)d_in[10];
    const float* gat2_w = (const float*)d_in[11];
    const float* att2_s = (const float*)d_in[12];
    const float* att2_d = (const float*)d_in[13];
    const float* gat2_b = (const float*)d_in[14];
    const float* ln2_g  = (const float*)d_in[15];
    const float* ln2_b  = (const float*)d_in[16];
    const float* gat3_w = (const float*)d_in[17];
    const float* att3_s = (const float*)d_in[18];
    const float* att3_d = (const float*)d_in[19];
    const float* gat3_b = (const float*)d_in[20];
    const float* ln3_g  = (const float*)d_in[21];
    const float* ln3_b  = (const float*)d_in[22];
    const float* cls1_w = (const float*)d_in[23];
    const float* cls1_b = (const float*)d_in[24];
    const float* cls2_w = (const float*)d_in[25];
    const float* cls2_b = (const float*)d_in[26];

    int Nn = in_sizes[0] / 768;
    int E  = in_sizes[1] / 2;
    int Gg = out_size;           // 32
    int Etot = E + Nn;
    int nb  = (Nn + 255) / 256;

    // ---- workspace layout (aligned to 256 B) ----
    char* w = (char*)d_ws;
    size_t off = 0;
    auto alloc = [&](size_t bytes) -> char* {
        char* r = w + off;
        off += (bytes + 255) & ~(size_t)255;
        return r;
    };
    size_t NB16 = (size_t)Nn * 1024 * sizeof(_Float16);
    size_t NB32 = (size_t)Nn * 1024 * sizeof(float);
    _Float16* P = (_Float16*)alloc(NB16);     // x16 -> h1 -> h2 -> h3
    _Float16* Q = (_Float16*)alloc(NB16);     // hproj16 -> x1_16 -> x2_16
    float*  X = (float*)alloc(NB32);          // x1/x2 fp32 resid chain -> x3
    _Float16* projT = (_Float16*)alloc((size_t)768 * 768 * 2);
    _Float16* g1T   = (_Float16*)alloc((size_t)1024 * 768 * 2);
    _Float16* g2T   = (_Float16*)alloc((size_t)1024 * 1024 * 2);
    _Float16* g3T   = (_Float16*)alloc((size_t)256 * 1024 * 2);
    float*    es    = (float*)alloc((size_t)Nn * 4 * 4);
    float*    ed_   = (float*)alloc((size_t)Nn * 4 * 4);
    int*      deg   = (int*)alloc((size_t)Nn * 4);
    int*      incl  = (int*)alloc((size_t)Nn * 4);
    int*      rowst = (int*)alloc((size_t)Nn * 4);
    int*      curs  = (int*)alloc((size_t)Nn * 4);
    int*      bsums = (int*)alloc((size_t)nb * 4);
    int*      csrc  = (int*)alloc((size_t)Etot * 4);
    float*    wse   = (float*)alloc((size_t)Etot * 4 * 4);
    float*    ps    = (float*)alloc((size_t)Gg * 256 * 4);
    unsigned* pm    = (unsigned*)alloc((size_t)Gg * 256 * 4);
    int*      cnt   = (int*)alloc(256);

    dim3 blk(256);

    // ---- weight transpose+convert (single batched launch: 2624 tiles) ----
    wt_all_kernel<<<dim3(2624), blk, 0, stream>>>(proj_w, projT, gat1_w, g1T,
                                                  gat2_w, g2T, gat3_w, g3T);

    // ---- x -> fp16 ----
    {
        size_t n4 = (size_t)Nn * 768 / 4;
        cvt_f16_kernel<<<dim3((unsigned)((n4 + 255) / 256)), blk, 0, stream>>>(x, P, n4);
    }

    // ---- CSR by dst ----
    csr_init<<<dim3(nb), blk, 0, stream>>>(deg, Nn);
    csr_count<<<dim3((E + 255) / 256), blk, 0, stream>>>(ei, deg, E);
    scan1<<<dim3(nb), blk, 0, stream>>>(deg, incl, bsums, Nn);
    scan2<<<dim3(1), dim3(64), 0, stream>>>(bsums, nb);
    scan3<<<dim3(nb), blk, 0, stream>>>(incl, deg, bsums, rowst, curs, Nn);
    csr_fill<<<dim3((Etot + 255) / 256), blk, 0, stream>>>(ei, curs, csrc, E, Nn);

    int mg = (Nn + 127) / 128;

    // proj: hproj16 = elu(x16 @ projW + b) -> Q
    gemm_f16<<<dim3(768 / 128, mg), blk, 0, stream>>>(P, projT, proj_b, Q, Nn, 768, 768, 1);

    auto run_gat = [&](const _Float16* xin16, const _Float16* WT, const float* as_, const float* ad_,
                       const float* gb, const float* lg, const float* lb, const float* resid,
                       _Float16* hbuf, float* xout, _Float16* xout16,
                       int K, int H, int C) {
        int HC = H * C;
        gemm_f16<<<dim3(HC / 128, mg), blk, 0, stream>>>(xin16, WT, nullptr, hbuf, Nn, K, HC, 0);
        int nw = Nn * H;
        attn_scores_kernel<<<dim3((nw + 3) / 4), blk, 0, stream>>>(hbuf, as_, ad_, es, ed_, Nn, H);
        if (H == 4) {
            seg_softmax<4><<<dim3((Nn + 3) / 4), blk, 0, stream>>>(rowst, deg, csrc, es, ed_, wse, Nn);
            gat_gather_ln<4><<<dim3(Nn), dim3(128), 0, stream>>>(rowst, deg, csrc, wse, hbuf,
                                                                 gb, lg, lb, resid, xout, xout16);
        } else {
            seg_softmax<1><<<dim3((Nn + 3) / 4), blk, 0, stream>>>(rowst, deg, csrc, es, ed_, wse, Nn);
            gat_gather_ln<1><<<dim3(Nn), dim3(64), 0, stream>>>(rowst, deg, csrc, wse, hbuf,
                                                                gb, lg, lb, resid, xout, xout16);
        }
    };

    // layer 1: 768 -> 4x256. A=Q(hproj) -> h1 in P; x1 -> X (fp32) + Q (fp16)
    run_gat(Q, g1T, att1_s, att1_d, gat1_b, ln1_g, ln1_b, nullptr, P, X, Q, 768, 4, 256);
    // layer 2: 1024 -> 4x256, resid x1 (X). A=Q(x1_16) -> h2 in P; x2 -> X in place + Q
    run_gat(Q, g2T, att2_s, att2_d, gat2_b, ln2_g, ln2_b, X, P, X, Q, 1024, 4, 256);
    // layer 3: 1024 -> 256 (1 head). A=Q(x2_16) -> h3 in P; x3 -> X fp32 only
    run_gat(Q, g3T, att3_s, att3_d, gat3_b, ln3_g, ln3_b, nullptr, P, X, nullptr, 1024, 1, 256);

    // pooling + classifier
    hipMemsetAsync(ps, 0, (size_t)Gg * 256 * 4, stream);
    hipMemsetAsync(pm, 0, (size_t)Gg * 256 * 4, stream);
    hipMemsetAsync(cnt, 0, (size_t)Gg * 4, stream);
    pool_kernel<<<dim3((Nn + 15) / 16), blk, 0, stream>>>(X, batch, ps, pm, cnt, Nn);
    classifier_kernel<<<dim3(Gg), dim3(128), 0, stream>>>(ps, pm, cnt, cls1_w, cls1_b, cls2_w, cls2_b, (float*)d_out);
}